// Round 3
// baseline (4177.388 us; speedup 1.0000x reference)
//
#include <hip/hip_runtime.h>
#include <math.h>

#define HH 96
#define WW 96
#define NWIN 65          // window size
#define NZ 160           // noise row stride
#define L33 33           // half-spectrum l range
#define PAD 36           // padded column stride
#define NT 256

// ---------------- kernel 1: shared sliding row-DFTs ----------------
// rd[r][px][l] = sum_{wx=0..64} noise[r][px+wx] * (cos,sin)(2*pi*l*wx/65)
__global__ __launch_bounds__(NT)
void rowdft_kernel(const float* __restrict__ noise, float2* __restrict__ rd)
{
    __shared__ float row[NZ];
    __shared__ float2 tw[NWIN];
    const int tid = threadIdx.x;
    const int r = blockIdx.x;
    if (tid < NWIN) {
        double a = 6.283185307179586 * (double)tid / 65.0;
        tw[tid] = make_float2((float)cos(a), (float)sin(a));
    }
    if (tid < NZ) row[tid] = noise[r * NZ + tid];
    __syncthreads();

    for (int t = tid; t < 96 * 9; t += NT) {
        const int px = t / 9;
        const int g = t - 9 * px;
        const int l0 = 4 * g;
        float c0[4], c1[4], s0[4], s1[4], tc2[4], aC[4], aS[4];
        #pragma unroll
        for (int j = 0; j < 4; j++) {
            float2 w = tw[l0 + j];      // l0+j <= 35 < 65
            c0[j] = 1.f; s0[j] = 0.f;
            c1[j] = w.x; s1[j] = w.y;
            tc2[j] = 2.f * w.x;
            aC[j] = 0.f; aS[j] = 0.f;
        }
        for (int wx = 0; wx < NWIN; ++wx) {
            float v = row[px + wx];     // broadcast within 9-lane groups
            #pragma unroll
            for (int j = 0; j < 4; j++) {
                aC[j] = fmaf(v, c0[j], aC[j]);
                aS[j] = fmaf(v, s0[j], aS[j]);
                float cn = fmaf(tc2[j], c1[j], -c0[j]);   // Chebyshev step
                float sn = fmaf(tc2[j], s1[j], -s0[j]);
                c0[j] = c1[j]; c1[j] = cn;
                s0[j] = s1[j]; s1[j] = sn;
            }
        }
        #pragma unroll
        for (int j = 0; j < 4; j++) {
            int l = l0 + j;
            if (l < L33) rd[(r * 96 + px) * L33 + l] = make_float2(aC[j], aS[j]);
        }
    }
}

// ---------------- kernel 2: per-pixel spectral pipeline ----------------
__global__ __launch_bounds__(NT, 4)
void fftma2_kernel(const float* __restrict__ angle,
                   const float2* __restrict__ rd,
                   float* __restrict__ out)
{
    __shared__ float2 tw[NWIN];                       // (cos,sin)(2*pi*m/65)
    __shared__ alignas(16) float  RbT[NWIN][PAD];     // R transposed [y][x], x in 0..32
    __shared__ alignas(16) float  Tc[L33][PAD];       // TR real part  [x][l]
    __shared__ alignas(16) float  Ts[L33][PAD];       // TR "sin" part [x][l]
    __shared__ alignas(16) float2 Wst[NWIN][PAD];     // rowdft staged [y][l]
    __shared__ float red[4][4];

    const int tid = threadIdx.x;
    const int p  = blockIdx.x;
    const int py = p / WW;
    const int px = p - py * WW;

    if (tid < NWIN) {
        double a = 6.283185307179586 * (double)tid / 65.0;
        tw[tid] = make_float2((float)cos(a), (float)sin(a));
    }

    const float th = angle[p];
    const float cth = cosf(th), sth = sinf(th);

    // ---- R build (x=0..32 only; centro-symmetry gives the other half) ----
    for (int e = tid; e < NWIN * PAD; e += NT) {
        int y = e / PAD, x = e - PAD * y;
        float v = 0.f;
        if (x < L33) {
            float X = (float)x;
            float Y = (float)(y <= 32 ? y : y - 65);
            float u =  X * cth + Y * sth;
            float w = -X * sth + Y * cth;
            float q = fmaf(u * (1.f / 225.f), u, w * (1.f / 9.f) * w);
            v = expf(-sqrtf(q));
        }
        RbT[y][x] = v;
    }
    // ---- stage rowdft into LDS (pad cols zeroed) ----
    for (int e = tid; e < NWIN * PAD; e += NT) {
        int y = e / PAD, l = e - PAD * y;
        float2 v = make_float2(0.f, 0.f);
        if (l < L33) v = rd[((py + y) * 96 + px) * L33 + l];
        Wst[y][l] = v;
    }
    __syncthreads();

    // ---- stage 3: TR[x][l] = sum_y RbT[y][x]*(cos,sin)(l*y) ----
    for (int t = tid; t < 9 * PAD; t += NT) {
        int xg = t / PAD, l = t - PAD * xg;
        int x0 = 4 * xg;
        float aC[4] = {0,0,0,0}, aS[4] = {0,0,0,0};
        int m = 0;
        for (int y = 0; y < NWIN; ++y) {
            float2 w = tw[m];
            const float4 rv = *(const float4*)&RbT[y][x0];   // broadcast
            aC[0] = fmaf(rv.x, w.x, aC[0]); aS[0] = fmaf(rv.x, w.y, aS[0]);
            aC[1] = fmaf(rv.y, w.x, aC[1]); aS[1] = fmaf(rv.y, w.y, aS[1]);
            aC[2] = fmaf(rv.z, w.x, aC[2]); aS[2] = fmaf(rv.z, w.y, aS[2]);
            aC[3] = fmaf(rv.w, w.x, aC[3]); aS[3] = fmaf(rv.w, w.y, aS[3]);
            m += l; if (m >= NWIN) m -= NWIN;
        }
        #pragma unroll
        for (int j = 0; j < 4; j++) {
            int x = x0 + j;
            if (x < L33) { Tc[x][l] = aC[j]; Ts[x][l] = aS[j]; }
        }
    }
    __syncthreads();

    // ---- per-bin: Rf fold + Wf col-DFT + csqrt + accumulation ----
    float accA = 0.f, accP = 0.f, accC = 0.f, accV = 0.f;
    for (int t = tid; t < 9 * NWIN; t += NT) {
        const int g = t / NWIN;
        const int k = t - NWIN * g;
        const int l0 = 4 * g;

        // Rf[k][l0..l0+3] = Tc[0][l] + 2*sum_{x=1..32}(cos(kx)Tc - sin(kx)Ts)
        const float4 tc0 = *(const float4*)&Tc[0][l0];
        float ac[4] = {0,0,0,0};
        int m = k;
        for (int x = 1; x < L33; ++x) {
            float2 w = tw[m];
            const float4 c = *(const float4*)&Tc[x][l0];     // broadcast
            const float4 s = *(const float4*)&Ts[x][l0];     // broadcast
            ac[0] = fmaf(c.x, w.x, ac[0]); ac[0] = fmaf(-s.x, w.y, ac[0]);
            ac[1] = fmaf(c.y, w.x, ac[1]); ac[1] = fmaf(-s.y, w.y, ac[1]);
            ac[2] = fmaf(c.z, w.x, ac[2]); ac[2] = fmaf(-s.z, w.y, ac[2]);
            ac[3] = fmaf(c.w, w.x, ac[3]); ac[3] = fmaf(-s.w, w.y, ac[3]);
            m += k; if (m >= NWIN) m -= NWIN;
        }
        float rf[4];
        rf[0] = fmaf(2.f, ac[0], tc0.x);
        rf[1] = fmaf(2.f, ac[1], tc0.y);
        rf[2] = fmaf(2.f, ac[2], tc0.z);
        rf[3] = fmaf(2.f, ac[3], tc0.w);

        // Wf[k][l0..l0+3] = sum_y rowdft[y][l]*(cos(ky) - i sin(ky))
        float Wr[4] = {0,0,0,0}, Wi[4] = {0,0,0,0};
        m = 0;
        for (int y = 0; y < NWIN; ++y) {
            float2 w = tw[m];
            const float4 w01 = *(const float4*)&Wst[y][l0];      // (Rc0,Rs0,Rc1,Rs1)
            const float4 w23 = *(const float4*)&Wst[y][l0 + 2];  // (Rc2,Rs2,Rc3,Rs3)
            Wr[0] = fmaf(w01.x, w.x, Wr[0]); Wr[0] = fmaf(-w01.y, w.y, Wr[0]);
            Wi[0] = fmaf(-w01.x, w.y, Wi[0]); Wi[0] = fmaf(-w01.y, w.x, Wi[0]);
            Wr[1] = fmaf(w01.z, w.x, Wr[1]); Wr[1] = fmaf(-w01.w, w.y, Wr[1]);
            Wi[1] = fmaf(-w01.z, w.y, Wi[1]); Wi[1] = fmaf(-w01.w, w.x, Wi[1]);
            Wr[2] = fmaf(w23.x, w.x, Wr[2]); Wr[2] = fmaf(-w23.y, w.y, Wr[2]);
            Wi[2] = fmaf(-w23.x, w.y, Wi[2]); Wi[2] = fmaf(-w23.y, w.x, Wi[2]);
            Wr[3] = fmaf(w23.z, w.x, Wr[3]); Wr[3] = fmaf(-w23.w, w.y, Wr[3]);
            Wi[3] = fmaf(-w23.z, w.y, Wi[3]); Wi[3] = fmaf(-w23.w, w.x, Wi[3]);
            m += k; if (m >= NWIN) m -= NWIN;
        }

        #pragma unroll
        for (int j = 0; j < 4; j++) {
            const int l = l0 + j;
            if (l > 32) continue;
            if (l == 0 && k > 32) continue;      // mirror of (65-k,0)
            float wr = Wr[j], wi = Wi[j];
            float rho = rf[j];
            int kl = k + l; if (kl >= NWIN) kl -= NWIN;
            float2 tkl = tw[kl];
            float zr = fmaf(rho, tkl.x, 1e-8f);
            float zi = rho * tkl.y;
            float rr = sqrtf(zr * zr + zi * zi);
            float Gr = sqrtf(fmaxf(0.5f * (rr + zr), 0.f));
            float Gm = sqrtf(fmaxf(0.5f * (rr - zr), 0.f));
            float Gi = (zi < 0.f) ? -Gm : Gm;     // principal csqrt
            float Fr = wr * Gr - wi * Gi;
            float Fi = wr * Gi + wi * Gr;
            if (k == 0 && l == 0) {
                accA += Fr * Fr + Fi * Fi;
                accP += Fr * Fr - Fi * Fi;
                accC += Fr;
                accV += Fr;
            } else {
                float Gi2 = (zi == 0.f) ? Gi : -Gi;   // branch-cut mirror
                float Fr2 = wr * Gr + wi * Gi2;
                float Fi2 = wr * Gi2 - wi * Gr;
                accA += Fr * Fr + Fi * Fi + Fr2 * Fr2 + Fi2 * Fi2;
                accP += 2.f * (Fr * Fr2 - Fi * Fi2);
                int m32 = (32 * (k + l)) % NWIN;
                float2 t32 = tw[m32];
                accC += Fr * t32.x - Fi * t32.y + Fr2 * t32.x + Fi2 * t32.y;
            }
        }
    }

    // ---- block reduction ----
    #pragma unroll
    for (int off = 32; off > 0; off >>= 1) {
        accA += __shfl_down(accA, off);
        accP += __shfl_down(accP, off);
        accC += __shfl_down(accC, off);
        accV += __shfl_down(accV, off);
    }
    int wv = tid >> 6, ln = tid & 63;
    if (ln == 0) { red[wv][0] = accA; red[wv][1] = accP; red[wv][2] = accC; red[wv][3] = accV; }
    __syncthreads();
    if (tid == 0) {
        float A  = red[0][0] + red[1][0] + red[2][0] + red[3][0];
        float P  = red[0][1] + red[1][1] + red[2][1] + red[3][1];
        float Cs = red[0][2] + red[1][2] + red[2][2] + red[3][2];
        float V  = red[0][3] + red[1][3] + red[2][3] + red[3][3];
        const float Ntot = 4225.f;
        float mean = V / Ntot;
        float E2   = (P + A) * (0.5f / Ntot);
        float cen  = Cs / Ntot;
        float var  = (E2 - Ntot * mean * mean) / (Ntot - 1.f);
        float sd   = sqrtf(fmaxf(var, 0.f));
        out[p] = (cen - mean) / (sd + 1e-6f);
    }
}

extern "C" void kernel_launch(void* const* d_in, const int* in_sizes, int n_in,
                              void* d_out, int out_size, void* d_ws, size_t ws_size,
                              hipStream_t stream)
{
    (void)in_sizes; (void)n_in; (void)out_size; (void)ws_size;
    const float* angle = (const float*)d_in[0];
    const float* noise = (const float*)d_in[1];
    float* outp = (float*)d_out;
    float2* rd = (float2*)d_ws;    // 160*96*33 float2 = 4.06 MB

    rowdft_kernel<<<dim3(NZ), dim3(NT), 0, stream>>>(noise, rd);
    fftma2_kernel<<<dim3(HH * WW), dim3(NT), 0, stream>>>(angle, rd, outp);
}

// Round 4
// 4046.491 us; speedup vs baseline: 1.0323x; 1.0323x over previous
//
#include <hip/hip_runtime.h>
#include <math.h>

#define HH 96
#define WW 96
#define NWIN 65          // window size
#define NZ 160           // noise row stride
#define L33 33           // half-spectrum l range
#define PAD 36           // padded column stride (floats / float2s)
#define NT 256

// ---------------- kernel 1: shared sliding row-DFTs ----------------
// rd2[px][r][l] = sum_{wx=0..64} noise[r][px+wx] * (cos,sin)(2*pi*l*wx/65)
// px-major layout so each fftma2 block reads ONE contiguous 17KB span.
__global__ __launch_bounds__(NT)
void rowdft_kernel(const float* __restrict__ noise, float2* __restrict__ rd)
{
    __shared__ float row[NZ];
    __shared__ float2 tw[NWIN];
    const int tid = threadIdx.x;
    const int r = blockIdx.x;
    if (tid < NWIN) {
        double a = 6.283185307179586 * (double)tid / 65.0;
        tw[tid] = make_float2((float)cos(a), (float)sin(a));
    }
    if (tid < NZ) row[tid] = noise[r * NZ + tid];
    __syncthreads();

    for (int t = tid; t < 96 * 9; t += NT) {
        const int px = t / 9;
        const int g = t - 9 * px;
        const int l0 = 4 * g;
        float c0[4], c1[4], s0[4], s1[4], tc2[4], aC[4], aS[4];
        #pragma unroll
        for (int j = 0; j < 4; j++) {
            float2 w = tw[l0 + j];      // l0+j <= 35 < 65
            c0[j] = 1.f; s0[j] = 0.f;
            c1[j] = w.x; s1[j] = w.y;
            tc2[j] = 2.f * w.x;
            aC[j] = 0.f; aS[j] = 0.f;
        }
        for (int wx = 0; wx < NWIN; ++wx) {
            float v = row[px + wx];     // broadcast within 9-lane groups
            #pragma unroll
            for (int j = 0; j < 4; j++) {
                aC[j] = fmaf(v, c0[j], aC[j]);
                aS[j] = fmaf(v, s0[j], aS[j]);
                float cn = fmaf(tc2[j], c1[j], -c0[j]);   // Chebyshev step
                float sn = fmaf(tc2[j], s1[j], -s0[j]);
                c0[j] = c1[j]; c1[j] = cn;
                s0[j] = s1[j]; s1[j] = sn;
            }
        }
        #pragma unroll
        for (int j = 0; j < 4; j++) {
            int l = l0 + j;
            if (l < L33) rd[(px * NZ + r) * L33 + l] = make_float2(aC[j], aS[j]);
        }
    }
}

// ---------------- kernel 2: per-pixel spectral pipeline ----------------
__global__ __launch_bounds__(NT, 4)
void fftma2_kernel(const float* __restrict__ angle,
                   const float2* __restrict__ rd,
                   float* __restrict__ out)
{
    __shared__ float2 tw[NWIN];                       // (cos,sin)(2*pi*m/65)
    __shared__ alignas(16) float  RbT[NWIN][PAD];     // R transposed [y][x], x in 0..32
    __shared__ alignas(16) float  Tc[L33][PAD];       // TR real part  [x][l]
    __shared__ alignas(16) float  Ts[L33][PAD];       // TR "sin" part [x][l]
    __shared__ alignas(16) float2 Wst[NWIN][PAD];     // rowdft staged [y][l]
    __shared__ float red[4][4];

    const int tid = threadIdx.x;
    const int p  = blockIdx.x;
    const int py = p / WW;
    const int px = p - py * WW;

    if (tid < NWIN) {
        double a = 6.283185307179586 * (double)tid / 65.0;
        tw[tid] = make_float2((float)cos(a), (float)sin(a));
    }

    const float th = angle[p];
    const float cth = cosf(th), sth = sinf(th);

    // ---- R build (x=0..32 only; centro-symmetry gives the other half) ----
    for (int e = tid; e < NWIN * PAD; e += NT) {
        int y = e / PAD, x = e - PAD * y;
        float v = 0.f;
        if (x < L33) {
            float X = (float)x;
            float Y = (float)(y <= 32 ? y : y - 65);
            float u =  X * cth + Y * sth;
            float w = -X * sth + Y * cth;
            float q = fmaf(u * (1.f / 225.f), u, w * (1.f / 9.f) * w);
            v = expf(-sqrtf(q));
        }
        RbT[y][x] = v;
    }
    // ---- stage rowdft into LDS (contiguous 17KB span; pad cols zeroed) ----
    {
        const float2* src = rd + (px * NZ + py) * L33;   // 65*33 contiguous float2
        for (int e = tid; e < NWIN * PAD; e += NT) {
            int y = e / PAD, l = e - PAD * y;
            float2 v = make_float2(0.f, 0.f);
            if (l < L33) v = src[y * L33 + l];           // coalesced 8B/lane
            Wst[y][l] = v;
        }
    }
    __syncthreads();

    // ---- stage 3: TR[x][l] = sum_y RbT[y][x]*(cos,sin)(l*y) ----
    for (int t = tid; t < 9 * PAD; t += NT) {
        int xg = t / PAD, l = t - PAD * xg;
        int x0 = 4 * xg;
        float aC[4] = {0,0,0,0}, aS[4] = {0,0,0,0};
        int m = 0;
        for (int y = 0; y < NWIN; ++y) {
            float2 w = tw[m];
            const float4 rv = *(const float4*)&RbT[y][x0];   // broadcast
            aC[0] = fmaf(rv.x, w.x, aC[0]); aS[0] = fmaf(rv.x, w.y, aS[0]);
            aC[1] = fmaf(rv.y, w.x, aC[1]); aS[1] = fmaf(rv.y, w.y, aS[1]);
            aC[2] = fmaf(rv.z, w.x, aC[2]); aS[2] = fmaf(rv.z, w.y, aS[2]);
            aC[3] = fmaf(rv.w, w.x, aC[3]); aS[3] = fmaf(rv.w, w.y, aS[3]);
            m += l; if (m >= NWIN) m -= NWIN;
        }
        #pragma unroll
        for (int j = 0; j < 4; j++) {
            int x = x0 + j;
            if (x < L33) { Tc[x][l] = aC[j]; Ts[x][l] = aS[j]; }
        }
    }
    __syncthreads();

    // ---- per-bin: Rf fold + Wf col-DFT + csqrt + accumulation ----
    float accA = 0.f, accP = 0.f, accC = 0.f, accV = 0.f;
    for (int t = tid; t < 9 * NWIN; t += NT) {
        const int g = t / NWIN;
        const int k = t - NWIN * g;
        const int l0 = 4 * g;

        // Rf[k][l0..l0+3] = Tc[0][l] + 2*sum_{x=1..32}(cos(kx)Tc - sin(kx)Ts)
        const float4 tc0 = *(const float4*)&Tc[0][l0];
        float ac[4] = {0,0,0,0};
        int m = k;
        for (int x = 1; x < L33; ++x) {
            float2 w = tw[m];
            const float4 c = *(const float4*)&Tc[x][l0];     // broadcast
            const float4 s = *(const float4*)&Ts[x][l0];     // broadcast
            ac[0] = fmaf(c.x, w.x, ac[0]); ac[0] = fmaf(-s.x, w.y, ac[0]);
            ac[1] = fmaf(c.y, w.x, ac[1]); ac[1] = fmaf(-s.y, w.y, ac[1]);
            ac[2] = fmaf(c.z, w.x, ac[2]); ac[2] = fmaf(-s.z, w.y, ac[2]);
            ac[3] = fmaf(c.w, w.x, ac[3]); ac[3] = fmaf(-s.w, w.y, ac[3]);
            m += k; if (m >= NWIN) m -= NWIN;
        }
        float rf[4];
        rf[0] = fmaf(2.f, ac[0], tc0.x);
        rf[1] = fmaf(2.f, ac[1], tc0.y);
        rf[2] = fmaf(2.f, ac[2], tc0.z);
        rf[3] = fmaf(2.f, ac[3], tc0.w);

        // Wf[k][l0..l0+3] = sum_y rowdft[y][l]*(cos(ky) - i sin(ky))
        float Wr[4] = {0,0,0,0}, Wi[4] = {0,0,0,0};
        m = 0;
        for (int y = 0; y < NWIN; ++y) {
            float2 w = tw[m];
            const float4 w01 = *(const float4*)&Wst[y][l0];      // (Rc0,Rs0,Rc1,Rs1)
            const float4 w23 = *(const float4*)&Wst[y][l0 + 2];  // (Rc2,Rs2,Rc3,Rs3)
            Wr[0] = fmaf(w01.x, w.x, Wr[0]); Wr[0] = fmaf(-w01.y, w.y, Wr[0]);
            Wi[0] = fmaf(-w01.x, w.y, Wi[0]); Wi[0] = fmaf(-w01.y, w.x, Wi[0]);
            Wr[1] = fmaf(w01.z, w.x, Wr[1]); Wr[1] = fmaf(-w01.w, w.y, Wr[1]);
            Wi[1] = fmaf(-w01.z, w.y, Wi[1]); Wi[1] = fmaf(-w01.w, w.x, Wi[1]);
            Wr[2] = fmaf(w23.x, w.x, Wr[2]); Wr[2] = fmaf(-w23.y, w.y, Wr[2]);
            Wi[2] = fmaf(-w23.x, w.y, Wi[2]); Wi[2] = fmaf(-w23.y, w.x, Wi[2]);
            Wr[3] = fmaf(w23.z, w.x, Wr[3]); Wr[3] = fmaf(-w23.w, w.y, Wr[3]);
            Wi[3] = fmaf(-w23.z, w.y, Wi[3]); Wi[3] = fmaf(-w23.w, w.x, Wi[3]);
            m += k; if (m >= NWIN) m -= NWIN;
        }

        #pragma unroll
        for (int j = 0; j < 4; j++) {
            const int l = l0 + j;
            if (l > 32) continue;
            if (l == 0 && k > 32) continue;      // mirror of (65-k,0)
            float wr = Wr[j], wi = Wi[j];
            float rho = rf[j];
            int kl = k + l; if (kl >= NWIN) kl -= NWIN;
            float2 tkl = tw[kl];
            float zr = fmaf(rho, tkl.x, 1e-8f);
            float zi = rho * tkl.y;
            float rr = sqrtf(zr * zr + zi * zi);
            float Gr = sqrtf(fmaxf(0.5f * (rr + zr), 0.f));
            float Gm = sqrtf(fmaxf(0.5f * (rr - zr), 0.f));
            float Gi = (zi < 0.f) ? -Gm : Gm;     // principal csqrt
            float Fr = wr * Gr - wi * Gi;
            float Fi = wr * Gi + wi * Gr;
            if (k == 0 && l == 0) {
                accA += Fr * Fr + Fi * Fi;
                accP += Fr * Fr - Fi * Fi;
                accC += Fr;
                accV += Fr;
            } else {
                float Gi2 = (zi == 0.f) ? Gi : -Gi;   // branch-cut mirror
                float Fr2 = wr * Gr + wi * Gi2;
                float Fi2 = wr * Gi2 - wi * Gr;
                accA += Fr * Fr + Fi * Fi + Fr2 * Fr2 + Fi2 * Fi2;
                accP += 2.f * (Fr * Fr2 - Fi * Fi2);
                int m32 = (32 * (k + l)) % NWIN;
                float2 t32 = tw[m32];
                accC += Fr * t32.x - Fi * t32.y + Fr2 * t32.x + Fi2 * t32.y;
            }
        }
    }

    // ---- block reduction ----
    #pragma unroll
    for (int off = 32; off > 0; off >>= 1) {
        accA += __shfl_down(accA, off);
        accP += __shfl_down(accP, off);
        accC += __shfl_down(accC, off);
        accV += __shfl_down(accV, off);
    }
    int wv = tid >> 6, ln = tid & 63;
    if (ln == 0) { red[wv][0] = accA; red[wv][1] = accP; red[wv][2] = accC; red[wv][3] = accV; }
    __syncthreads();
    if (tid == 0) {
        float A  = red[0][0] + red[1][0] + red[2][0] + red[3][0];
        float P  = red[0][1] + red[1][1] + red[2][1] + red[3][1];
        float Cs = red[0][2] + red[1][2] + red[2][2] + red[3][2];
        float V  = red[0][3] + red[1][3] + red[2][3] + red[3][3];
        const float Ntot = 4225.f;
        float mean = V / Ntot;
        float E2   = (P + A) * (0.5f / Ntot);
        float cen  = Cs / Ntot;
        float var  = (E2 - Ntot * mean * mean) / (Ntot - 1.f);
        float sd   = sqrtf(fmaxf(var, 0.f));
        out[p] = (cen - mean) / (sd + 1e-6f);
    }
}

extern "C" void kernel_launch(void* const* d_in, const int* in_sizes, int n_in,
                              void* d_out, int out_size, void* d_ws, size_t ws_size,
                              hipStream_t stream)
{
    (void)in_sizes; (void)n_in; (void)out_size; (void)ws_size;
    const float* angle = (const float*)d_in[0];
    const float* noise = (const float*)d_in[1];
    float* outp = (float*)d_out;
    float2* rd = (float2*)d_ws;    // 96*160*33 float2 = 4.06 MB, [px][r][l]

    rowdft_kernel<<<dim3(NZ), dim3(NT), 0, stream>>>(noise, rd);
    fftma2_kernel<<<dim3(HH * WW), dim3(NT), 0, stream>>>(angle, rd, outp);
}

// Round 5
// 1202.830 us; speedup vs baseline: 3.4730x; 3.3641x over previous
//
#include <hip/hip_runtime.h>
#include <math.h>

#define HH 96
#define WW 96
#define NWIN 65          // window size
#define NZ 160           // noise row stride
#define L33 33           // half-spectrum l range
#define PAD 36           // padded column stride (floats / float2s)
#define NT 256

// ---------------- kernel 1: shared sliding row-DFTs ----------------
// rd2[px][r][l] = sum_{wx=0..64} noise[r][px+wx] * (cos,sin)(2*pi*l*wx/65)
// px-major layout so each fftma2 block reads ONE contiguous 17KB span.
__global__ __launch_bounds__(NT)
void rowdft_kernel(const float* __restrict__ noise, float2* __restrict__ rd)
{
    __shared__ float row[NZ];
    __shared__ float2 tw[NWIN];
    const int tid = threadIdx.x;
    const int r = blockIdx.x;
    if (tid < NWIN) {
        double a = 6.283185307179586 * (double)tid / 65.0;
        tw[tid] = make_float2((float)cos(a), (float)sin(a));
    }
    if (tid < NZ) row[tid] = noise[r * NZ + tid];
    __syncthreads();

    for (int t = tid; t < 96 * 9; t += NT) {
        const int px = t / 9;
        const int g = t - 9 * px;
        const int l0 = 4 * g;
        float c0[4], c1[4], s0[4], s1[4], tc2[4], aC[4], aS[4];
        #pragma unroll
        for (int j = 0; j < 4; j++) {
            float2 w = tw[l0 + j];      // l0+j <= 35 < 65
            c0[j] = 1.f; s0[j] = 0.f;
            c1[j] = w.x; s1[j] = w.y;
            tc2[j] = 2.f * w.x;
            aC[j] = 0.f; aS[j] = 0.f;
        }
        for (int wx = 0; wx < NWIN; ++wx) {
            float v = row[px + wx];     // broadcast within 9-lane groups
            #pragma unroll
            for (int j = 0; j < 4; j++) {
                aC[j] = fmaf(v, c0[j], aC[j]);
                aS[j] = fmaf(v, s0[j], aS[j]);
                float cn = fmaf(tc2[j], c1[j], -c0[j]);   // Chebyshev step
                float sn = fmaf(tc2[j], s1[j], -s0[j]);
                c0[j] = c1[j]; c1[j] = cn;
                s0[j] = s1[j]; s1[j] = sn;
            }
        }
        #pragma unroll
        for (int j = 0; j < 4; j++) {
            int l = l0 + j;
            if (l < L33) rd[(px * NZ + r) * L33 + l] = make_float2(aC[j], aS[j]);
        }
    }
}

// ---------------- kernel 2: per-pixel spectral pipeline ----------------
// NOTE: no min-waves clamp. Round-3/4's __launch_bounds__(NT,4) forced
// VGPR=64 and spilled the inner-loop accumulators to scratch -> 14.5 GB/launch
// of spill traffic (FETCH 9.4GB / WRITE 5GB), latency-bound at VALUBusy 11%.
__global__ __launch_bounds__(NT)
void fftma2_kernel(const float* __restrict__ angle,
                   const float2* __restrict__ rd,
                   float* __restrict__ out)
{
    __shared__ float2 tw[NWIN];                       // (cos,sin)(2*pi*m/65)
    __shared__ alignas(16) float  RbT[NWIN][PAD];     // R transposed [y][x], x in 0..32
    __shared__ alignas(16) float  Tc[L33][PAD];       // TR real part  [x][l]
    __shared__ alignas(16) float  Ts[L33][PAD];       // TR "sin" part [x][l]
    __shared__ alignas(16) float2 Wst[NWIN][PAD];     // rowdft staged [y][l]
    __shared__ float red[4][4];

    const int tid = threadIdx.x;
    const int p  = blockIdx.x;
    const int py = p / WW;
    const int px = p - py * WW;

    if (tid < NWIN) {
        double a = 6.283185307179586 * (double)tid / 65.0;
        tw[tid] = make_float2((float)cos(a), (float)sin(a));
    }

    const float th = angle[p];
    const float cth = cosf(th), sth = sinf(th);

    // ---- R build (x=0..32 only; centro-symmetry gives the other half) ----
    for (int e = tid; e < NWIN * PAD; e += NT) {
        int y = e / PAD, x = e - PAD * y;
        float v = 0.f;
        if (x < L33) {
            float X = (float)x;
            float Y = (float)(y <= 32 ? y : y - 65);
            float u =  X * cth + Y * sth;
            float w = -X * sth + Y * cth;
            float q = fmaf(u * (1.f / 225.f), u, w * (1.f / 9.f) * w);
            v = expf(-sqrtf(q));
        }
        RbT[y][x] = v;
    }
    // ---- stage rowdft into LDS (contiguous 17KB span; pad cols zeroed) ----
    {
        const float2* src = rd + (px * NZ + py) * L33;   // 65*33 contiguous float2
        for (int e = tid; e < NWIN * PAD; e += NT) {
            int y = e / PAD, l = e - PAD * y;
            float2 v = make_float2(0.f, 0.f);
            if (l < L33) v = src[y * L33 + l];           // coalesced 8B/lane
            Wst[y][l] = v;
        }
    }
    __syncthreads();

    // ---- stage 3: TR[x][l] = sum_y RbT[y][x]*(cos,sin)(l*y) ----
    for (int t = tid; t < 9 * PAD; t += NT) {
        int xg = t / PAD, l = t - PAD * xg;
        int x0 = 4 * xg;
        float aC[4] = {0,0,0,0}, aS[4] = {0,0,0,0};
        int m = 0;
        for (int y = 0; y < NWIN; ++y) {
            float2 w = tw[m];
            const float4 rv = *(const float4*)&RbT[y][x0];   // broadcast
            aC[0] = fmaf(rv.x, w.x, aC[0]); aS[0] = fmaf(rv.x, w.y, aS[0]);
            aC[1] = fmaf(rv.y, w.x, aC[1]); aS[1] = fmaf(rv.y, w.y, aS[1]);
            aC[2] = fmaf(rv.z, w.x, aC[2]); aS[2] = fmaf(rv.z, w.y, aS[2]);
            aC[3] = fmaf(rv.w, w.x, aC[3]); aS[3] = fmaf(rv.w, w.y, aS[3]);
            m += l; if (m >= NWIN) m -= NWIN;
        }
        #pragma unroll
        for (int j = 0; j < 4; j++) {
            int x = x0 + j;
            if (x < L33) { Tc[x][l] = aC[j]; Ts[x][l] = aS[j]; }
        }
    }
    __syncthreads();

    // ---- per-bin: Rf fold + Wf col-DFT + csqrt + accumulation ----
    float accA = 0.f, accP = 0.f, accC = 0.f, accV = 0.f;
    for (int t = tid; t < 9 * NWIN; t += NT) {
        const int g = t / NWIN;
        const int k = t - NWIN * g;
        const int l0 = 4 * g;

        // Rf[k][l0..l0+3] = Tc[0][l] + 2*sum_{x=1..32}(cos(kx)Tc - sin(kx)Ts)
        const float4 tc0 = *(const float4*)&Tc[0][l0];
        float ac[4] = {0,0,0,0};
        int m = k;
        for (int x = 1; x < L33; ++x) {
            float2 w = tw[m];
            const float4 c = *(const float4*)&Tc[x][l0];     // broadcast
            const float4 s = *(const float4*)&Ts[x][l0];     // broadcast
            ac[0] = fmaf(c.x, w.x, ac[0]); ac[0] = fmaf(-s.x, w.y, ac[0]);
            ac[1] = fmaf(c.y, w.x, ac[1]); ac[1] = fmaf(-s.y, w.y, ac[1]);
            ac[2] = fmaf(c.z, w.x, ac[2]); ac[2] = fmaf(-s.z, w.y, ac[2]);
            ac[3] = fmaf(c.w, w.x, ac[3]); ac[3] = fmaf(-s.w, w.y, ac[3]);
            m += k; if (m >= NWIN) m -= NWIN;
        }
        float rf[4];
        rf[0] = fmaf(2.f, ac[0], tc0.x);
        rf[1] = fmaf(2.f, ac[1], tc0.y);
        rf[2] = fmaf(2.f, ac[2], tc0.z);
        rf[3] = fmaf(2.f, ac[3], tc0.w);

        // Wf[k][l0..l0+3] = sum_y rowdft[y][l]*(cos(ky) - i sin(ky))
        float Wr[4] = {0,0,0,0}, Wi[4] = {0,0,0,0};
        m = 0;
        for (int y = 0; y < NWIN; ++y) {
            float2 w = tw[m];
            const float4 w01 = *(const float4*)&Wst[y][l0];      // (Rc0,Rs0,Rc1,Rs1)
            const float4 w23 = *(const float4*)&Wst[y][l0 + 2];  // (Rc2,Rs2,Rc3,Rs3)
            Wr[0] = fmaf(w01.x, w.x, Wr[0]); Wr[0] = fmaf(-w01.y, w.y, Wr[0]);
            Wi[0] = fmaf(-w01.x, w.y, Wi[0]); Wi[0] = fmaf(-w01.y, w.x, Wi[0]);
            Wr[1] = fmaf(w01.z, w.x, Wr[1]); Wr[1] = fmaf(-w01.w, w.y, Wr[1]);
            Wi[1] = fmaf(-w01.z, w.y, Wi[1]); Wi[1] = fmaf(-w01.w, w.x, Wi[1]);
            Wr[2] = fmaf(w23.x, w.x, Wr[2]); Wr[2] = fmaf(-w23.y, w.y, Wr[2]);
            Wi[2] = fmaf(-w23.x, w.y, Wi[2]); Wi[2] = fmaf(-w23.y, w.x, Wi[2]);
            Wr[3] = fmaf(w23.z, w.x, Wr[3]); Wr[3] = fmaf(-w23.w, w.y, Wr[3]);
            Wi[3] = fmaf(-w23.z, w.y, Wi[3]); Wi[3] = fmaf(-w23.w, w.x, Wi[3]);
            m += k; if (m >= NWIN) m -= NWIN;
        }

        #pragma unroll
        for (int j = 0; j < 4; j++) {
            const int l = l0 + j;
            if (l > 32) continue;
            if (l == 0 && k > 32) continue;      // mirror of (65-k,0)
            float wr = Wr[j], wi = Wi[j];
            float rho = rf[j];
            int kl = k + l; if (kl >= NWIN) kl -= NWIN;
            float2 tkl = tw[kl];
            float zr = fmaf(rho, tkl.x, 1e-8f);
            float zi = rho * tkl.y;
            float rr = sqrtf(zr * zr + zi * zi);
            float Gr = sqrtf(fmaxf(0.5f * (rr + zr), 0.f));
            float Gm = sqrtf(fmaxf(0.5f * (rr - zr), 0.f));
            float Gi = (zi < 0.f) ? -Gm : Gm;     // principal csqrt
            float Fr = wr * Gr - wi * Gi;
            float Fi = wr * Gi + wi * Gr;
            if (k == 0 && l == 0) {
                accA += Fr * Fr + Fi * Fi;
                accP += Fr * Fr - Fi * Fi;
                accC += Fr;
                accV += Fr;
            } else {
                float Gi2 = (zi == 0.f) ? Gi : -Gi;   // branch-cut mirror
                float Fr2 = wr * Gr + wi * Gi2;
                float Fi2 = wr * Gi2 - wi * Gr;
                accA += Fr * Fr + Fi * Fi + Fr2 * Fr2 + Fi2 * Fi2;
                accP += 2.f * (Fr * Fr2 - Fi * Fi2);
                int m32 = (32 * (k + l)) % NWIN;
                float2 t32 = tw[m32];
                accC += Fr * t32.x - Fi * t32.y + Fr2 * t32.x + Fi2 * t32.y;
            }
        }
    }

    // ---- block reduction ----
    #pragma unroll
    for (int off = 32; off > 0; off >>= 1) {
        accA += __shfl_down(accA, off);
        accP += __shfl_down(accP, off);
        accC += __shfl_down(accC, off);
        accV += __shfl_down(accV, off);
    }
    int wv = tid >> 6, ln = tid & 63;
    if (ln == 0) { red[wv][0] = accA; red[wv][1] = accP; red[wv][2] = accC; red[wv][3] = accV; }
    __syncthreads();
    if (tid == 0) {
        float A  = red[0][0] + red[1][0] + red[2][0] + red[3][0];
        float P  = red[0][1] + red[1][1] + red[2][1] + red[3][1];
        float Cs = red[0][2] + red[1][2] + red[2][2] + red[3][2];
        float V  = red[0][3] + red[1][3] + red[2][3] + red[3][3];
        const float Ntot = 4225.f;
        float mean = V / Ntot;
        float E2   = (P + A) * (0.5f / Ntot);
        float cen  = Cs / Ntot;
        float var  = (E2 - Ntot * mean * mean) / (Ntot - 1.f);
        float sd   = sqrtf(fmaxf(var, 0.f));
        out[p] = (cen - mean) / (sd + 1e-6f);
    }
}

extern "C" void kernel_launch(void* const* d_in, const int* in_sizes, int n_in,
                              void* d_out, int out_size, void* d_ws, size_t ws_size,
                              hipStream_t stream)
{
    (void)in_sizes; (void)n_in; (void)out_size; (void)ws_size;
    const float* angle = (const float*)d_in[0];
    const float* noise = (const float*)d_in[1];
    float* outp = (float*)d_out;
    float2* rd = (float2*)d_ws;    // 96*160*33 float2 = 4.06 MB, [px][r][l]

    rowdft_kernel<<<dim3(NZ), dim3(NT), 0, stream>>>(noise, rd);
    fftma2_kernel<<<dim3(HH * WW), dim3(NT), 0, stream>>>(angle, rd, outp);
}

// Round 10
// 874.504 us; speedup vs baseline: 4.7769x; 1.3754x over previous
//
#include <hip/hip_runtime.h>
#include <math.h>

#define HH 96
#define WW 96
#define NWIN 65          // window size
#define NZ 160           // noise row stride
#define L33 33           // half-spectrum l range
#define PAD 36           // padded column stride (floats / float2s)
#define NT 256
#define KT 3             // k-tile per task
#define NG 22            // ceil(65/KT) k-triples; NG*9 = 198 main tasks

// ---------------- kernel 1: shared sliding row-DFTs ----------------
// rd2[px][r][l]: px-major so each fftma2 block reads ONE contiguous 17KB span.
__global__ __launch_bounds__(NT)
void rowdft_kernel(const float* __restrict__ noise, float2* __restrict__ rd)
{
    __shared__ float row[NZ];
    __shared__ float2 tw[NWIN];
    const int tid = threadIdx.x;
    const int r = blockIdx.x;
    if (tid < NWIN) {
        double a = 6.283185307179586 * (double)tid / 65.0;
        tw[tid] = make_float2((float)cos(a), (float)sin(a));
    }
    if (tid < NZ) row[tid] = noise[r * NZ + tid];
    __syncthreads();

    for (int t = tid; t < 96 * 9; t += NT) {
        const int px = t / 9;
        const int g = t - 9 * px;
        const int l0 = 4 * g;
        float c0[4], c1[4], s0[4], s1[4], tc2[4], aC[4], aS[4];
        #pragma unroll
        for (int j = 0; j < 4; j++) {
            float2 w = tw[l0 + j];      // l0+j <= 35 < 65
            c0[j] = 1.f; s0[j] = 0.f;
            c1[j] = w.x; s1[j] = w.y;
            tc2[j] = 2.f * w.x;
            aC[j] = 0.f; aS[j] = 0.f;
        }
        for (int wx = 0; wx < NWIN; ++wx) {
            float v = row[px + wx];
            #pragma unroll
            for (int j = 0; j < 4; j++) {
                aC[j] = fmaf(v, c0[j], aC[j]);
                aS[j] = fmaf(v, s0[j], aS[j]);
                float cn = fmaf(tc2[j], c1[j], -c0[j]);   // Chebyshev step
                float sn = fmaf(tc2[j], s1[j], -s0[j]);
                c0[j] = c1[j]; c1[j] = cn;
                s0[j] = s1[j]; s1[j] = sn;
            }
        }
        #pragma unroll
        for (int j = 0; j < 4; j++) {
            int l = l0 + j;
            if (l < L33) rd[(px * NZ + r) * L33 + l] = make_float2(aC[j], aS[j]);
        }
    }
}

// ---------------- kernel 2: per-pixel spectral pipeline ----------------
// LDS-throughput optimized: k-tile x3 per task (b128 reads reused 3x) and
// register Chebyshev twiddles (no tw[m] LDS gathers in hot loops).
__global__ __launch_bounds__(NT)
void fftma2_kernel(const float* __restrict__ angle,
                   const float2* __restrict__ rd,
                   float* __restrict__ out)
{
    __shared__ float2 tw[NWIN];                       // (cos,sin)(2*pi*m/65) - epilogue only
    __shared__ alignas(16) float  RbT[NWIN][PAD];     // R transposed [y][x], x in 0..32
    __shared__ alignas(16) float  Tc[L33][PAD];       // TR real part  [x][l]
    __shared__ alignas(16) float  Ts[L33][PAD];       // TR "sin" part [x][l]
    __shared__ alignas(16) float2 Wst[NWIN][PAD];     // rowdft staged [y][l]
    __shared__ float red[4][4];

    const int tid = threadIdx.x;
    const int p  = blockIdx.x;
    const int py = p / WW;
    const int px = p - py * WW;

    if (tid < NWIN) {
        double a = 6.283185307179586 * (double)tid / 65.0;
        tw[tid] = make_float2((float)cos(a), (float)sin(a));
    }

    const float th = angle[p];
    const float cth = cosf(th), sth = sinf(th);

    // ---- R build (x=0..32 only; centro-symmetry gives the other half) ----
    for (int e = tid; e < NWIN * PAD; e += NT) {
        int y = e / PAD, x = e - PAD * y;
        float v = 0.f;
        if (x < L33) {
            float X = (float)x;
            float Y = (float)(y <= 32 ? y : y - 65);
            float u =  X * cth + Y * sth;
            float w = -X * sth + Y * cth;
            float q = fmaf(u * (1.f / 225.f), u, w * (1.f / 9.f) * w);
            v = expf(-sqrtf(q));
        }
        RbT[y][x] = v;
    }
    // ---- stage rowdft into LDS (contiguous 17KB span; pad cols zeroed) ----
    {
        const float2* src = rd + (px * NZ + py) * L33;   // 65*33 contiguous float2
        for (int e = tid; e < NWIN * PAD; e += NT) {
            int y = e / PAD, l = e - PAD * y;
            float2 v = make_float2(0.f, 0.f);
            if (l < L33) v = src[y * L33 + l];           // coalesced 8B/lane
            Wst[y][l] = v;
        }
    }
    __syncthreads();

    // ---- stage 3: TR[x][l] = sum_y RbT[y][x]*(cos,sin)(l*y), cheb twiddles ----
    for (int t = tid; t < 9 * PAD; t += NT) {
        int xg = t / PAD, l = t - PAD * xg;
        int x0 = 4 * xg;
        float aC[4] = {0,0,0,0}, aS[4] = {0,0,0,0};
        float2 wl = tw[l];                // l <= 35 < 65
        float cm = 1.f, sm = 0.f;         // (cos,sin)(l*0)
        float cc = wl.x, ss = wl.y;       // (cos,sin)(l*1)
        float t2 = 2.f * wl.x;
        for (int y = 0; y < NWIN; ++y) {
            const float4 rv = *(const float4*)&RbT[y][x0];   // broadcast
            aC[0] = fmaf(rv.x, cm, aC[0]); aS[0] = fmaf(rv.x, sm, aS[0]);
            aC[1] = fmaf(rv.y, cm, aC[1]); aS[1] = fmaf(rv.y, sm, aS[1]);
            aC[2] = fmaf(rv.z, cm, aC[2]); aS[2] = fmaf(rv.z, sm, aS[2]);
            aC[3] = fmaf(rv.w, cm, aC[3]); aS[3] = fmaf(rv.w, sm, aS[3]);
            float cn = fmaf(t2, cc, -cm);
            float sn = fmaf(t2, ss, -sm);
            cm = cc; sm = ss; cc = cn; ss = sn;
        }
        #pragma unroll
        for (int j = 0; j < 4; j++) {
            int x = x0 + j;
            if (x < L33) { Tc[x][l] = aC[j]; Ts[x][l] = aS[j]; }
        }
    }
    __syncthreads();

    // ---- per-task (k-triple, l-quad): Rf fold + Wf col-DFT + csqrt + accum ----
    float accA = 0.f, accP = 0.f, accC = 0.f, accV = 0.f;
    if (tid < NG * 9) {
        const int g  = tid / 9;
        const int lg = tid - 9 * g;
        const int l0 = 4 * lg;
        const int kb = KT * g;            // k = kb, kb+1, kb+2 (kb+2 may be 65 -> masked)

        // Chebyshev step constants per k
        float stc2[KT], sc1[KT], ss1[KT];
        #pragma unroll
        for (int d = 0; d < KT; d++) {
            int kc = kb + d; if (kc >= NWIN) kc -= NWIN;
            float2 w = tw[kc];
            sc1[d] = w.x; ss1[d] = w.y; stc2[d] = 2.f * w.x;
        }

        // ---- Rf fold: rf = Tc[0][l] + 2*sum_{x=1..32}(cos(kx)Tc - sin(kx)Ts) ----
        const float4 tc0 = *(const float4*)&Tc[0][l0];
        float ac[KT][4];
        #pragma unroll
        for (int d = 0; d < KT; d++)
            #pragma unroll
            for (int j = 0; j < 4; j++) ac[d][j] = 0.f;
        {
            float cm[KT], sm[KT], cc[KT], ss[KT];
            #pragma unroll
            for (int d = 0; d < KT; d++) {
                cm[d] = 1.f; sm[d] = 0.f;        // x=0
                cc[d] = sc1[d]; ss[d] = ss1[d];  // x=1
            }
            for (int x = 1; x < L33; ++x) {
                const float4 c4 = *(const float4*)&Tc[x][l0];
                const float4 s4 = *(const float4*)&Ts[x][l0];
                #pragma unroll
                for (int d = 0; d < KT; d++) {
                    float cw = cc[d], sw = ss[d];    // (cos,sin)(k*x)
                    ac[d][0] = fmaf(c4.x, cw, ac[d][0]); ac[d][0] = fmaf(-s4.x, sw, ac[d][0]);
                    ac[d][1] = fmaf(c4.y, cw, ac[d][1]); ac[d][1] = fmaf(-s4.y, sw, ac[d][1]);
                    ac[d][2] = fmaf(c4.z, cw, ac[d][2]); ac[d][2] = fmaf(-s4.z, sw, ac[d][2]);
                    ac[d][3] = fmaf(c4.w, cw, ac[d][3]); ac[d][3] = fmaf(-s4.w, sw, ac[d][3]);
                    float cn = fmaf(stc2[d], cw, -cm[d]);
                    float sn = fmaf(stc2[d], sw, -sm[d]);
                    cm[d] = cw; sm[d] = sw; cc[d] = cn; ss[d] = sn;
                }
            }
        }

        // ---- Wf col-DFT: Wf[k][l] = sum_y (aC - i aS)[y][l] * (cos - i sin)(k*y) ----
        float Wr[KT][4], Wi[KT][4];
        #pragma unroll
        for (int d = 0; d < KT; d++)
            #pragma unroll
            for (int j = 0; j < 4; j++) { Wr[d][j] = 0.f; Wi[d][j] = 0.f; }
        {
            float cm[KT], sm[KT], cc[KT], ss[KT];
            #pragma unroll
            for (int d = 0; d < KT; d++) {
                cm[d] = 1.f; sm[d] = 0.f;        // y=0
                cc[d] = sc1[d]; ss[d] = ss1[d];  // y=1
            }
            for (int y = 0; y < NWIN; ++y) {
                const float4 w01 = *(const float4*)&Wst[y][l0];      // (Rc0,Rs0,Rc1,Rs1)
                const float4 w23 = *(const float4*)&Wst[y][l0 + 2];  // (Rc2,Rs2,Rc3,Rs3)
                #pragma unroll
                for (int d = 0; d < KT; d++) {
                    float cw = cm[d], sw = sm[d];    // (cos,sin)(k*y)
                    Wr[d][0] = fmaf(w01.x, cw, Wr[d][0]); Wr[d][0] = fmaf(-w01.y, sw, Wr[d][0]);
                    Wi[d][0] = fmaf(-w01.x, sw, Wi[d][0]); Wi[d][0] = fmaf(-w01.y, cw, Wi[d][0]);
                    Wr[d][1] = fmaf(w01.z, cw, Wr[d][1]); Wr[d][1] = fmaf(-w01.w, sw, Wr[d][1]);
                    Wi[d][1] = fmaf(-w01.z, sw, Wi[d][1]); Wi[d][1] = fmaf(-w01.w, cw, Wi[d][1]);
                    Wr[d][2] = fmaf(w23.x, cw, Wr[d][2]); Wr[d][2] = fmaf(-w23.y, sw, Wr[d][2]);
                    Wi[d][2] = fmaf(-w23.x, sw, Wi[d][2]); Wi[d][2] = fmaf(-w23.y, cw, Wi[d][2]);
                    Wr[d][3] = fmaf(w23.z, cw, Wr[d][3]); Wr[d][3] = fmaf(-w23.w, sw, Wr[d][3]);
                    Wi[d][3] = fmaf(-w23.z, sw, Wi[d][3]); Wi[d][3] = fmaf(-w23.w, cw, Wi[d][3]);
                    float cn = fmaf(stc2[d], cc[d], -cw);
                    float sn = fmaf(stc2[d], ss[d], -sw);
                    cm[d] = cc[d]; sm[d] = ss[d]; cc[d] = cn; ss[d] = sn;
                }
            }
        }

        // ---- epilogue: csqrt + spectral accumulation ----
        #pragma unroll
        for (int d = 0; d < KT; d++) {
            const int k = kb + d;
            if (k >= NWIN) continue;
            #pragma unroll
            for (int j = 0; j < 4; j++) {
                const int l = l0 + j;
                if (l > 32) continue;
                if (l == 0 && k > 32) continue;      // mirror of (65-k,0)
                float wr = Wr[d][j], wi = Wi[d][j];
                float rho = fmaf(2.f, ac[d][j], (j==0)?tc0.x:(j==1)?tc0.y:(j==2)?tc0.z:tc0.w);
                int kl = k + l; if (kl >= NWIN) kl -= NWIN;
                float2 tkl = tw[kl];
                float zr = fmaf(rho, tkl.x, 1e-8f);
                float zi = rho * tkl.y;
                float rr = sqrtf(zr * zr + zi * zi);
                float Gr = sqrtf(fmaxf(0.5f * (rr + zr), 0.f));
                float Gm = sqrtf(fmaxf(0.5f * (rr - zr), 0.f));
                float Gi = (zi < 0.f) ? -Gm : Gm;     // principal csqrt
                float Fr = wr * Gr - wi * Gi;
                float Fi = wr * Gi + wi * Gr;
                if (k == 0 && l == 0) {
                    accA += Fr * Fr + Fi * Fi;
                    accP += Fr * Fr - Fi * Fi;
                    accC += Fr;
                    accV += Fr;
                } else {
                    float Gi2 = (zi == 0.f) ? Gi : -Gi;   // branch-cut mirror
                    float Fr2 = wr * Gr + wi * Gi2;
                    float Fi2 = wr * Gi2 - wi * Gr;
                    accA += Fr * Fr + Fi * Fi + Fr2 * Fr2 + Fi2 * Fi2;
                    accP += 2.f * (Fr * Fr2 - Fi * Fi2);
                    int m32 = (32 * (k + l)) % NWIN;
                    float2 t32 = tw[m32];
                    accC += Fr * t32.x - Fi * t32.y + Fr2 * t32.x + Fi2 * t32.y;
                }
            }
        }
    }

    // ---- block reduction ----
    #pragma unroll
    for (int off = 32; off > 0; off >>= 1) {
        accA += __shfl_down(accA, off);
        accP += __shfl_down(accP, off);
        accC += __shfl_down(accC, off);
        accV += __shfl_down(accV, off);
    }
    int wv = tid >> 6, ln = tid & 63;
    if (ln == 0) { red[wv][0] = accA; red[wv][1] = accP; red[wv][2] = accC; red[wv][3] = accV; }
    __syncthreads();
    if (tid == 0) {
        float A  = red[0][0] + red[1][0] + red[2][0] + red[3][0];
        float P  = red[0][1] + red[1][1] + red[2][1] + red[3][1];
        float Cs = red[0][2] + red[1][2] + red[2][2] + red[3][2];
        float V  = red[0][3] + red[1][3] + red[2][3] + red[3][3];
        const float Ntot = 4225.f;
        float mean = V / Ntot;
        float E2   = (P + A) * (0.5f / Ntot);
        float cen  = Cs / Ntot;
        float var  = (E2 - Ntot * mean * mean) / (Ntot - 1.f);
        float sd   = sqrtf(fmaxf(var, 0.f));
        out[p] = (cen - mean) / (sd + 1e-6f);
    }
}

extern "C" void kernel_launch(void* const* d_in, const int* in_sizes, int n_in,
                              void* d_out, int out_size, void* d_ws, size_t ws_size,
                              hipStream_t stream)
{
    (void)in_sizes; (void)n_in; (void)out_size; (void)ws_size;
    const float* angle = (const float*)d_in[0];
    const float* noise = (const float*)d_in[1];
    float* outp = (float*)d_out;
    float2* rd = (float2*)d_ws;    // 96*160*33 float2 = 4.06 MB, [px][r][l]

    rowdft_kernel<<<dim3(NZ), dim3(NT), 0, stream>>>(noise, rd);
    fftma2_kernel<<<dim3(HH * WW), dim3(NT), 0, stream>>>(angle, rd, outp);
}

// Round 11
// 765.354 us; speedup vs baseline: 5.4581x; 1.1426x over previous
//
#include <hip/hip_runtime.h>
#include <math.h>

#define HH 96
#define WW 96
#define NWIN 65          // window size
#define NZ 160           // noise row stride
#define L33 33           // half-spectrum l range
#define PAD 36           // padded column stride (floats / float2s)
#define NT1 256          // rowdft block
#define NT2 192          // fftma2 block (3 waves; 153 main tasks)

// ---------------- kernel 1: shared sliding row-DFTs ----------------
// rd[px][r][l]: px-major so each fftma2 block reads ONE contiguous 17KB span.
__global__ __launch_bounds__(NT1)
void rowdft_kernel(const float* __restrict__ noise, float2* __restrict__ rd)
{
    __shared__ float row[NZ];
    __shared__ float2 tw[NWIN];
    const int tid = threadIdx.x;
    const int r = blockIdx.x;
    if (tid < NWIN) {
        double a = 6.283185307179586 * (double)tid / 65.0;
        tw[tid] = make_float2((float)cos(a), (float)sin(a));
    }
    if (tid < NZ) row[tid] = noise[r * NZ + tid];
    __syncthreads();

    for (int t = tid; t < 96 * 9; t += NT1) {
        const int px = t / 9;
        const int g = t - 9 * px;
        const int l0 = 4 * g;
        float c0[4], c1[4], s0[4], s1[4], tc2[4], aC[4], aS[4];
        #pragma unroll
        for (int j = 0; j < 4; j++) {
            float2 w = tw[l0 + j];      // l0+j <= 35 < 65
            c0[j] = 1.f; s0[j] = 0.f;
            c1[j] = w.x; s1[j] = w.y;
            tc2[j] = 2.f * w.x;
            aC[j] = 0.f; aS[j] = 0.f;
        }
        for (int wx = 0; wx < NWIN; ++wx) {
            float v = row[px + wx];
            #pragma unroll
            for (int j = 0; j < 4; j++) {
                aC[j] = fmaf(v, c0[j], aC[j]);
                aS[j] = fmaf(v, s0[j], aS[j]);
                float cn = fmaf(tc2[j], c1[j], -c0[j]);   // Chebyshev step
                float sn = fmaf(tc2[j], s1[j], -s0[j]);
                c0[j] = c1[j]; c1[j] = cn;
                s0[j] = s1[j]; s1[j] = sn;
            }
        }
        #pragma unroll
        for (int j = 0; j < 4; j++) {
            int l = l0 + j;
            if (l < L33) rd[(px * NZ + r) * L33 + l] = make_float2(aC[j], aS[j]);
        }
    }
}

// ---------------- kernel 2: per-pixel spectral pipeline ----------------
// k<->65-k pairing: A,B,C,D partial sums give BOTH Wf[k] and Wf[65-k] for the
// price of one. Task = (2 k-pairs, l-quad): 17*9=153 tasks on 192 threads.
__global__ __launch_bounds__(NT2)
void fftma2_kernel(const float* __restrict__ angle,
                   const float2* __restrict__ rd,
                   float* __restrict__ out)
{
    __shared__ float2 tw[NWIN];                       // setup/epilogue only
    __shared__ alignas(16) float  RbT[NWIN][PAD];     // R transposed [y][x], x 0..32
    __shared__ alignas(16) float  Tc[L33][PAD];       // TR real part  [x][l]
    __shared__ alignas(16) float  Ts[L33][PAD];       // TR sin part   [x][l]
    __shared__ alignas(16) float2 Wst[NWIN][PAD];     // rowdft staged [y][l]
    __shared__ float red[3][4];

    const int tid = threadIdx.x;
    const int p  = blockIdx.x;
    const int py = p / WW;
    const int px = p - py * WW;

    if (tid < NWIN) {
        double a = 6.283185307179586 * (double)tid / 65.0;
        tw[tid] = make_float2((float)cos(a), (float)sin(a));
    }

    const float th = angle[p];
    const float cth = cosf(th), sth = sinf(th);

    // ---- R build (x=0..32; centro-symmetry gives the rest) ----
    for (int e = tid; e < NWIN * PAD; e += NT2) {
        int y = e / PAD, x = e - PAD * y;
        float v = 0.f;
        if (x < L33) {
            float X = (float)x;
            float Y = (float)(y <= 32 ? y : y - 65);
            float u =  X * cth + Y * sth;
            float w = -X * sth + Y * cth;
            float q = fmaf(u * (1.f / 225.f), u, w * (1.f / 9.f) * w);
            v = expf(-sqrtf(q));
        }
        RbT[y][x] = v;
    }
    // ---- stage rowdft into LDS (contiguous 17KB span; pad zeroed) ----
    {
        const float2* src = rd + (px * NZ + py) * L33;
        for (int e = tid; e < NWIN * PAD; e += NT2) {
            int y = e / PAD, l = e - PAD * y;
            float2 v = make_float2(0.f, 0.f);
            if (l < L33) v = src[y * L33 + l];
            Wst[y][l] = v;
        }
    }
    __syncthreads();

    // ---- stage 3: TR[x][l] = sum_y RbT[y][x]*(cos,sin)(l*y), cheb twiddles ----
    for (int t = tid; t < 9 * PAD; t += NT2) {
        int xg = t / PAD, l = t - PAD * xg;
        int x0 = 4 * xg;
        float aC[4] = {0,0,0,0}, aS[4] = {0,0,0,0};
        float2 wl = tw[l];
        float cm = 1.f, sm = 0.f;
        float cc = wl.x, ss = wl.y;
        float t2 = 2.f * wl.x;
        for (int y = 0; y < NWIN; ++y) {
            const float4 rv = *(const float4*)&RbT[y][x0];
            aC[0] = fmaf(rv.x, cm, aC[0]); aS[0] = fmaf(rv.x, sm, aS[0]);
            aC[1] = fmaf(rv.y, cm, aC[1]); aS[1] = fmaf(rv.y, sm, aS[1]);
            aC[2] = fmaf(rv.z, cm, aC[2]); aS[2] = fmaf(rv.z, sm, aS[2]);
            aC[3] = fmaf(rv.w, cm, aC[3]); aS[3] = fmaf(rv.w, sm, aS[3]);
            float cn = fmaf(t2, cc, -cm);
            float sn = fmaf(t2, ss, -sm);
            cm = cc; sm = ss; cc = cn; ss = sn;
        }
        #pragma unroll
        for (int j = 0; j < 4; j++) {
            int x = x0 + j;
            if (x < L33) { Tc[x][l] = aC[j]; Ts[x][l] = aS[j]; }
        }
    }
    __syncthreads();

    // ---- per-task (2 k-pairs, l-quad) ----
    float accA = 0.f, accP = 0.f, accC = 0.f, accV = 0.f;
    if (tid < 17 * 9) {
        const int g  = tid / 9;
        const int lg = tid - 9 * g;
        const int l0 = 4 * lg;
        // pair d: kp_d = 2g+d  (kp=33 at g=16,d=1 is computed but masked)

        float sc1[2], ss1[2], st2[2];
        #pragma unroll
        for (int d = 0; d < 2; d++) {
            float2 w = tw[2 * g + d];    // 2g+d <= 33 < 65
            sc1[d] = w.x; ss1[d] = w.y; st2[d] = 2.f * w.x;
        }
        const float4 tc0 = *(const float4*)&Tc[0][l0];

        // ---- Rf fold, paired: P=sum c*cos, Q=sum s*sin ----
        float P[2][4], Q[2][4];
        #pragma unroll
        for (int d = 0; d < 2; d++)
            #pragma unroll
            for (int j = 0; j < 4; j++) { P[d][j] = 0.f; Q[d][j] = 0.f; }
        {
            float cm[2] = {1.f, 1.f}, sm[2] = {0.f, 0.f};
            float cc[2] = {sc1[0], sc1[1]}, ss[2] = {ss1[0], ss1[1]};
            for (int x = 1; x < L33; ++x) {
                const float4 c4 = *(const float4*)&Tc[x][l0];
                const float4 s4 = *(const float4*)&Ts[x][l0];
                #pragma unroll
                for (int d = 0; d < 2; d++) {
                    float cw = cc[d], sw = ss[d];      // (cos,sin)(k*x)
                    P[d][0] = fmaf(c4.x, cw, P[d][0]); Q[d][0] = fmaf(s4.x, sw, Q[d][0]);
                    P[d][1] = fmaf(c4.y, cw, P[d][1]); Q[d][1] = fmaf(s4.y, sw, Q[d][1]);
                    P[d][2] = fmaf(c4.z, cw, P[d][2]); Q[d][2] = fmaf(s4.z, sw, Q[d][2]);
                    P[d][3] = fmaf(c4.w, cw, P[d][3]); Q[d][3] = fmaf(s4.w, sw, Q[d][3]);
                    float cn = fmaf(st2[d], cw, -cm[d]);
                    float sn = fmaf(st2[d], sw, -sm[d]);
                    cm[d] = cw; sm[d] = sw; cc[d] = cn; ss[d] = sn;
                }
            }
        }
        float rfm[2][4], rfp[2][4];       // rho for k and for 65-k
        #pragma unroll
        for (int d = 0; d < 2; d++)
            #pragma unroll
            for (int j = 0; j < 4; j++) {
                float t0 = (j == 0) ? tc0.x : (j == 1) ? tc0.y : (j == 2) ? tc0.z : tc0.w;
                rfm[d][j] = fmaf(2.f, P[d][j] - Q[d][j], t0);
                rfp[d][j] = fmaf(2.f, P[d][j] + Q[d][j], t0);
            }

        // ---- Wf col-DFT, paired: A=wc*cos B=ws*sin C=wc*sin D=ws*cos ----
        float A[2][4], B[2][4], C[2][4], D[2][4];
        #pragma unroll
        for (int d = 0; d < 2; d++)
            #pragma unroll
            for (int j = 0; j < 4; j++) { A[d][j] = 0.f; B[d][j] = 0.f; C[d][j] = 0.f; D[d][j] = 0.f; }
        {
            float cm[2] = {1.f, 1.f}, sm[2] = {0.f, 0.f};
            float cc[2] = {sc1[0], sc1[1]}, ss[2] = {ss1[0], ss1[1]};
            for (int y = 0; y < NWIN; ++y) {
                const float4 w01 = *(const float4*)&Wst[y][l0];      // (wc0,ws0,wc1,ws1)
                const float4 w23 = *(const float4*)&Wst[y][l0 + 2];  // (wc2,ws2,wc3,ws3)
                #pragma unroll
                for (int d = 0; d < 2; d++) {
                    float cw = cm[d], sw = sm[d];      // (cos,sin)(k*y)
                    A[d][0] = fmaf(w01.x, cw, A[d][0]); B[d][0] = fmaf(w01.y, sw, B[d][0]);
                    C[d][0] = fmaf(w01.x, sw, C[d][0]); D[d][0] = fmaf(w01.y, cw, D[d][0]);
                    A[d][1] = fmaf(w01.z, cw, A[d][1]); B[d][1] = fmaf(w01.w, sw, B[d][1]);
                    C[d][1] = fmaf(w01.z, sw, C[d][1]); D[d][1] = fmaf(w01.w, cw, D[d][1]);
                    A[d][2] = fmaf(w23.x, cw, A[d][2]); B[d][2] = fmaf(w23.y, sw, B[d][2]);
                    C[d][2] = fmaf(w23.x, sw, C[d][2]); D[d][2] = fmaf(w23.y, cw, D[d][2]);
                    A[d][3] = fmaf(w23.z, cw, A[d][3]); B[d][3] = fmaf(w23.w, sw, B[d][3]);
                    C[d][3] = fmaf(w23.z, sw, C[d][3]); D[d][3] = fmaf(w23.w, cw, D[d][3]);
                    float cn = fmaf(st2[d], cc[d], -cw);
                    float sn = fmaf(st2[d], ss[d], -sw);
                    cm[d] = cc[d]; sm[d] = ss[d]; cc[d] = cn; ss[d] = sn;
                }
            }
        }

        // ---- epilogue: both k of each pair; csqrt + accumulate ----
        #pragma unroll
        for (int d = 0; d < 2; d++) {
            const int kp = 2 * g + d;
            if (kp > 32) continue;              // masked pair (g=16,d=1)
            #pragma unroll
            for (int e = 0; e < 2; e++) {
                if (e == 1 && kp == 0) continue;   // 65-0 doesn't exist
                const int kk = e ? (65 - kp) : kp;
                #pragma unroll
                for (int j = 0; j < 4; j++) {
                    const int l = l0 + j;
                    if (l > 32) continue;
                    if (l == 0 && kk > 32) continue;   // mirror of (65-kk,0)
                    float wr  = e ? (A[d][j] + B[d][j]) : (A[d][j] - B[d][j]);
                    float wi  = e ? (C[d][j] - D[d][j]) : (-(C[d][j] + D[d][j]));
                    float rho = e ? rfp[d][j] : rfm[d][j];
                    int kl = kk + l; if (kl >= NWIN) kl -= NWIN;
                    float2 tkl = tw[kl];
                    float zr = fmaf(rho, tkl.x, 1e-8f);
                    float zi = rho * tkl.y;
                    float rr = sqrtf(zr * zr + zi * zi);
                    float Gr = sqrtf(fmaxf(0.5f * (rr + zr), 0.f));
                    float Gm = sqrtf(fmaxf(0.5f * (rr - zr), 0.f));
                    float Gi = (zi < 0.f) ? -Gm : Gm;   // principal csqrt
                    float Fr = wr * Gr - wi * Gi;
                    float Fi = wr * Gi + wi * Gr;
                    if (kk == 0 && l == 0) {
                        accA += Fr * Fr + Fi * Fi;
                        accP += Fr * Fr - Fi * Fi;
                        accC += Fr;
                        accV += Fr;
                    } else {
                        float Gi2 = (zi == 0.f) ? Gi : -Gi;   // branch-cut mirror
                        float Fr2 = wr * Gr + wi * Gi2;
                        float Fi2 = wr * Gi2 - wi * Gr;
                        accA += Fr * Fr + Fi * Fi + Fr2 * Fr2 + Fi2 * Fi2;
                        accP += 2.f * (Fr * Fr2 - Fi * Fi2);
                        int m32 = (32 * (kk + l)) % NWIN;
                        float2 t32 = tw[m32];
                        accC += Fr * t32.x - Fi * t32.y + Fr2 * t32.x + Fi2 * t32.y;
                    }
                }
            }
        }
    }

    // ---- block reduction (3 waves) ----
    #pragma unroll
    for (int off = 32; off > 0; off >>= 1) {
        accA += __shfl_down(accA, off);
        accP += __shfl_down(accP, off);
        accC += __shfl_down(accC, off);
        accV += __shfl_down(accV, off);
    }
    int wv = tid >> 6, ln = tid & 63;
    if (ln == 0) { red[wv][0] = accA; red[wv][1] = accP; red[wv][2] = accC; red[wv][3] = accV; }
    __syncthreads();
    if (tid == 0) {
        float Asum = red[0][0] + red[1][0] + red[2][0];
        float Psum = red[0][1] + red[1][1] + red[2][1];
        float Csum = red[0][2] + red[1][2] + red[2][2];
        float Vsum = red[0][3] + red[1][3] + red[2][3];
        const float Ntot = 4225.f;
        float mean = Vsum / Ntot;
        float E2   = (Psum + Asum) * (0.5f / Ntot);
        float cen  = Csum / Ntot;
        float var  = (E2 - Ntot * mean * mean) / (Ntot - 1.f);
        float sd   = sqrtf(fmaxf(var, 0.f));
        out[p] = (cen - mean) / (sd + 1e-6f);
    }
}

extern "C" void kernel_launch(void* const* d_in, const int* in_sizes, int n_in,
                              void* d_out, int out_size, void* d_ws, size_t ws_size,
                              hipStream_t stream)
{
    (void)in_sizes; (void)n_in; (void)out_size; (void)ws_size;
    const float* angle = (const float*)d_in[0];
    const float* noise = (const float*)d_in[1];
    float* outp = (float*)d_out;
    float2* rd = (float2*)d_ws;    // 96*160*33 float2 = 4.06 MB, [px][r][l]

    rowdft_kernel<<<dim3(NZ), dim3(NT1), 0, stream>>>(noise, rd);
    fftma2_kernel<<<dim3(HH * WW), dim3(NT2), 0, stream>>>(angle, rd, outp);
}